// Round 1
// baseline (659.491 us; speedup 1.0000x reference)
//
#include <hip/hip_runtime.h>
#include <stdint.h>

#define HV 384
#define WV 384
#define HF 96
#define WF 96
#define NC 128
#define NB 32
#define NSTORM 50
#define TFRAMES 12
#define MIN_INT 0.3f

// ---- peak predicate: v > 0.3 and no element of the 8x8 symmetric-reflected
// window (rows i-4..i+3, cols j-4..j+3) strictly exceeds v.
__device__ __forceinline__ bool is_peak(const float* __restrict__ vb, int p) {
    int i = p / WV, j = p % WV;
    float v = vb[p];
    if (!(v > MIN_INT)) return false;
    for (int dr = -4; dr <= 3; ++dr) {
        int rr = i + dr;
        rr = (rr < 0) ? (-rr - 1) : ((rr >= HV) ? (2 * HV - 1 - rr) : rr);
        const float* row = vb + rr * WV;
        for (int dc = -4; dc <= 3; ++dc) {
            int cc = j + dc;
            cc = (cc < 0) ? (-cc - 1) : ((cc >= WV) ? (2 * WV - 1 - cc) : cc);
            if (row[cc] > v) return false;
        }
    }
    return true;
}

// ---- kernel 1: detect peaks, compact (key = value_bits<<32 | ~idx) per batch
__global__ void peak_kernel(const float* __restrict__ vil,
                            uint64_t* __restrict__ cand,
                            int* __restrict__ cnt, int cap) {
    int b = blockIdx.y;
    int p = blockIdx.x * blockDim.x + threadIdx.x;   // grid covers exactly HV*WV
    const float* vb = vil + (size_t)b * TFRAMES * (HV * WV)
                          + (size_t)(TFRAMES - 1) * (HV * WV);
    float v = vb[p];
    if (!(v > MIN_INT)) return;
    int i = p / WV, j = p % WV;
    for (int dr = -4; dr <= 3; ++dr) {
        int rr = i + dr;
        rr = (rr < 0) ? (-rr - 1) : ((rr >= HV) ? (2 * HV - 1 - rr) : rr);
        const float* row = vb + rr * WV;
        for (int dc = -4; dc <= 3; ++dc) {
            int cc = j + dc;
            cc = (cc < 0) ? (-cc - 1) : ((cc >= WV) ? (2 * WV - 1 - cc) : cc);
            if (row[cc] > v) return;
        }
    }
    int pos = atomicAdd(cnt + b, 1);
    if (pos < cap) {
        uint64_t key = ((uint64_t)__float_as_uint(v) << 32)
                     | (uint64_t)(0xFFFFFFFFu - (uint32_t)p);
        cand[(size_t)b * cap + pos] = key;
    }
}

// ---- kernel 2: per batch, pick top-50 keys (desc value, ties -> lower idx).
// Order-independent w.r.t. compaction order (strict total order on keys).
__global__ void select_kernel(const uint64_t* __restrict__ cand,
                              const int* __restrict__ cnt, int cap,
                              const float* __restrict__ vil,
                              int* __restrict__ sel_idx,
                              int* __restrict__ sel_valid) {
    int b = blockIdx.x;
    int tid = threadIdx.x;
    int n = cnt[b]; if (n > cap) n = cap;
    int K = n < NSTORM ? n : NSTORM;
    const uint64_t* ck = cand + (size_t)b * cap;

    __shared__ uint64_t red[256];
    __shared__ uint64_t prev_s;
    uint64_t prev = ~0ull;

    for (int t = 0; t < K; ++t) {
        uint64_t best = 0;
        for (int k = tid; k < n; k += 256) {
            uint64_t key = ck[k];
            if (key < prev && key > best) best = key;
        }
        red[tid] = best;
        __syncthreads();
        for (int s = 128; s > 0; s >>= 1) {
            if (tid < s) { uint64_t o = red[tid + s]; if (o > red[tid]) red[tid] = o; }
            __syncthreads();
        }
        if (tid == 0) {
            uint64_t w = red[0];
            prev_s = w;
            sel_idx[b * NSTORM + t] = (int)(0xFFFFFFFFu - (uint32_t)(w & 0xFFFFFFFFu));
            sel_valid[b * NSTORM + t] = 1;
        }
        __syncthreads();
        prev = prev_s;
        __syncthreads();
    }

    // Fallback paths (dead with this data: ~1600 peaks/batch >> 50).
    // top_k on -inf entries returns ascending non-peak indices; then if there
    // were zero peaks, slot 0 is overridden with the grid center (valid=1).
    if (tid == 0 && K < NSTORM) {
        const float* vb = vil + (size_t)b * TFRAMES * (HV * WV)
                              + (size_t)(TFRAMES - 1) * (HV * WV);
        int f = 0;
        for (int t = K; t < NSTORM; ++t) {
            while (f < HV * WV && is_peak(vb, f)) ++f;
            sel_idx[b * NSTORM + t] = f;
            sel_valid[b * NSTORM + t] = 0;
            ++f;
        }
        if (n == 0) {
            sel_idx[b * NSTORM + 0] = (HV / 2) * WV + (WV / 2);
            sel_valid[b * NSTORM + 0] = 1;
        }
    }
}

// ---- kernel 3: gather feature column + 128x128 matvec + bias, write outputs
__global__ void project_kernel(const float* __restrict__ features,
                               const float* __restrict__ proj_w,
                               const float* __restrict__ proj_b,
                               const int* __restrict__ sel_idx,
                               const int* __restrict__ sel_valid,
                               float* __restrict__ out) {
    int blk = blockIdx.x;           // [0, NB*NSTORM)
    int b = blk / NSTORM;
    int m = blk % NSTORM;
    int tid = threadIdx.x;          // 0..127 = output dim d (and gather chan c)

    int idx = sel_idx[b * NSTORM + m];
    int vld = sel_valid[b * NSTORM + m];
    int y = idx / WV, x = idx % WV;
    int yf = y >> 2; if (yf > HF - 1) yf = HF - 1;
    int xf = x >> 2; if (xf > WF - 1) xf = WF - 1;
    int lin = yf * WF + xf;

    __shared__ float g[NC];
    g[tid] = features[((size_t)b * NC + tid) * (HF * WF) + lin];
    __syncthreads();

    float acc = 0.f;
    const float* wr = proj_w + (size_t)tid * NC;   // row d of proj_w (d,c)
    #pragma unroll 8
    for (int c = 0; c < NC; ++c) acc += g[c] * wr[c];

    float* feat_out = out;                          // (NB, NSTORM, NC)
    feat_out[((size_t)b * NSTORM + m) * NC + tid] = vld ? (acc + proj_b[tid]) : 0.f;

    if (tid == 0) {
        float* pos_out = out + (size_t)NB * NSTORM * NC;        // (NB, NSTORM, 2)
        pos_out[(b * NSTORM + m) * 2 + 0] = (float)yf;
        pos_out[(b * NSTORM + m) * 2 + 1] = (float)xf;
        float* valid_out = out + (size_t)NB * NSTORM * NC + (size_t)NB * NSTORM * 2;
        valid_out[b * NSTORM + m] = vld ? 1.f : 0.f;
    }
}

extern "C" void kernel_launch(void* const* d_in, const int* in_sizes, int n_in,
                              void* d_out, int out_size, void* d_ws, size_t ws_size,
                              hipStream_t stream) {
    const float* features = (const float*)d_in[0];  // (32,128,96,96)
    const float* vil      = (const float*)d_in[1];  // (32,12,384,384)
    const float* proj_w   = (const float*)d_in[2];  // (128,128)
    const float* proj_b   = (const float*)d_in[3];  // (128,)
    float* out = (float*)d_out;

    uint8_t* ws = (uint8_t*)d_ws;
    int* cnt       = (int*)ws;                       // 32 ints
    int* sel_idx   = (int*)(ws + 256);               // 1600 ints
    int* sel_valid = (int*)(ws + 256 + NB * NSTORM * sizeof(int));
    uint64_t* cand = (uint64_t*)(ws + 16384);        // aligned

    size_t avail = (ws_size > 16384) ? (ws_size - 16384) : 0;
    int cap = (int)(avail / (NB * sizeof(uint64_t)));
    if (cap > 8192) cap = 8192;
    if (cap < 1)    cap = 1;

    hipMemsetAsync(cnt, 0, NB * sizeof(int), stream);

    dim3 gA((HV * WV) / 256, NB);
    peak_kernel<<<gA, 256, 0, stream>>>(vil, cand, cnt, cap);
    select_kernel<<<NB, 256, 0, stream>>>(cand, cnt, cap, vil, sel_idx, sel_valid);
    project_kernel<<<NB * NSTORM, 128, 0, stream>>>(features, proj_w, proj_b,
                                                    sel_idx, sel_valid, out);
}

// Round 2
// 489.143 us; speedup vs baseline: 1.3483x; 1.3483x over previous
//
#include <hip/hip_runtime.h>
#include <stdint.h>

#define HV 384
#define WV 384
#define HF 96
#define WF 96
#define NC 128
#define NB 32
#define NSTORM 50
#define TFRAMES 12
#define MIN_INT 0.3f

// peak tile geometry: each block produces a TH x TW block of the peak mask.
// Window is rows i-4..i+3, cols j-4..j+3 (lo=4, hi=3) with symmetric reflect.
#define TW 64
#define TH 32

__device__ __forceinline__ int reflect_idx(int g, int n) {
    if (g < 0) return -g - 1;
    if (g >= n) return 2 * n - 1 - g;
    return g;
}

// ---- slow scalar peak predicate, used only on the dead fallback path
__device__ __forceinline__ bool is_peak(const float* __restrict__ vb, int p) {
    int i = p / WV, j = p % WV;
    float v = vb[p];
    if (!(v > MIN_INT)) return false;
    for (int dr = -4; dr <= 3; ++dr) {
        const float* row = vb + reflect_idx(i + dr, HV) * WV;
        for (int dc = -4; dc <= 3; ++dc)
            if (row[reflect_idx(j + dc, WV)] > v) return false;
    }
    return true;
}

// ---- kernel 1: separable 8x8 max filter on LDS tiles, compact peak keys.
// key = (float_bits(v) << 32) | ~idx  — strict total order, so later
// selection is deterministic regardless of atomic compaction order.
__global__ void peak_kernel(const float* __restrict__ vil,
                            uint64_t* __restrict__ cand,
                            int* __restrict__ cnt, int cap) {
    __shared__ float A[TH + 7][TW + 8];   // input tile + halo (cols padded)
    __shared__ float Bm[TH + 7][TW];      // horizontal max (rows keep halo)

    int b = blockIdx.z;
    int tx0 = blockIdx.x * TW;
    int ty0 = blockIdx.y * TH;
    int tid = threadIdx.x;                // 256 threads
    const float* vb = vil + ((size_t)b * TFRAMES + (TFRAMES - 1)) * (HV * WV);

    for (int k = tid; k < (TH + 7) * (TW + 7); k += 256) {
        int r = k / (TW + 7), c = k % (TW + 7);
        int gr = reflect_idx(ty0 + r - 4, HV);
        int gc = reflect_idx(tx0 + c - 4, WV);
        A[r][c] = vb[gr * WV + gc];
    }
    __syncthreads();

    // horizontal: Bm[r][c] = max(A[r][c..c+7])  (out col c uses A cols c..c+7)
    for (int k = tid; k < (TH + 7) * TW; k += 256) {
        int r = k / TW, c = k % TW;
        float m = A[r][c];
        #pragma unroll
        for (int d = 1; d < 8; ++d) m = fmaxf(m, A[r][c + d]);
        Bm[r][c] = m;
    }
    __syncthreads();

    // vertical + predicate: out pixel (r,c) uses Bm rows r..r+7
    for (int k = tid; k < TH * TW; k += 256) {
        int r = k / TW, c = k % TW;
        float v = A[r + 4][c + 4];
        if (v > MIN_INT) {
            float m = Bm[r][c];
            #pragma unroll
            for (int d = 1; d < 8; ++d) m = fmaxf(m, Bm[r + d][c]);
            if (m <= v) {                  // window max == v  -> peak
                int p = (ty0 + r) * WV + (tx0 + c);
                int pos = atomicAdd(cnt + b, 1);
                if (pos < cap)
                    cand[(size_t)b * cap + pos] =
                        ((uint64_t)__float_as_uint(v) << 32)
                        | (uint64_t)(0xFFFFFFFFu - (uint32_t)p);
            }
        }
    }
}

// ---- kernel 2: per batch, top-50 keys (desc value, ties -> lower idx)
#define SEL_CAP 4096
__global__ void select_kernel(const uint64_t* __restrict__ cand,
                              const int* __restrict__ cnt, int cap,
                              const float* __restrict__ vil,
                              int* __restrict__ sel_idx,
                              int* __restrict__ sel_valid) {
    __shared__ uint64_t keys[SEL_CAP];    // 32 KB stage
    __shared__ uint64_t wred[4];
    __shared__ uint64_t bcast;

    int b = blockIdx.x;
    int tid = threadIdx.x;                // 256
    int n = cnt[b]; if (n > cap) n = cap;
    int K = n < NSTORM ? n : NSTORM;
    const uint64_t* ck = cand + (size_t)b * cap;

    bool lds = (n <= SEL_CAP);
    if (lds) for (int k = tid; k < n; k += 256) keys[k] = ck[k];
    __syncthreads();

    uint64_t prev = ~0ull;
    for (int t = 0; t < K; ++t) {
        uint64_t best = 0;
        if (lds) { for (int k = tid; k < n; k += 256) { uint64_t key = keys[k]; if (key < prev && key > best) best = key; } }
        else     { for (int k = tid; k < n; k += 256) { uint64_t key = ck[k];   if (key < prev && key > best) best = key; } }
        #pragma unroll
        for (int off = 32; off > 0; off >>= 1) {
            uint64_t o = __shfl_xor(best, off);
            if (o > best) best = o;
        }
        if ((tid & 63) == 0) wred[tid >> 6] = best;
        __syncthreads();
        if (tid == 0) {
            uint64_t w = wred[0];
            #pragma unroll
            for (int i = 1; i < 4; ++i) if (wred[i] > w) w = wred[i];
            bcast = w;
            sel_idx[b * NSTORM + t] = (int)(0xFFFFFFFFu - (uint32_t)(w & 0xFFFFFFFFu));
            sel_valid[b * NSTORM + t] = 1;
        }
        __syncthreads();
        prev = bcast;
    }

    // Fallback (dead with this data: ~2300 peaks/batch >> 50): top_k on -inf
    // rows yields ascending non-peak indices; zero peaks -> center, valid.
    if (tid == 0 && K < NSTORM) {
        const float* vb = vil + ((size_t)b * TFRAMES + (TFRAMES - 1)) * (HV * WV);
        int f = 0;
        for (int t = K; t < NSTORM; ++t) {
            while (f < HV * WV && is_peak(vb, f)) ++f;
            sel_idx[b * NSTORM + t] = f;
            sel_valid[b * NSTORM + t] = 0;
            ++f;
        }
        if (n == 0) {
            sel_idx[b * NSTORM + 0] = (HV / 2) * WV + (WV / 2);
            sel_valid[b * NSTORM + 0] = 1;
        }
    }
}

// ---- kernel 3: gather feature column + 128x128 matvec + bias
__global__ void project_kernel(const float* __restrict__ features,
                               const float* __restrict__ proj_w,
                               const float* __restrict__ proj_b,
                               const int* __restrict__ sel_idx,
                               const int* __restrict__ sel_valid,
                               float* __restrict__ out) {
    int blk = blockIdx.x;
    int b = blk / NSTORM;
    int m = blk % NSTORM;
    int tid = threadIdx.x;                // 0..127

    int idx = sel_idx[b * NSTORM + m];
    int vld = sel_valid[b * NSTORM + m];
    int y = idx / WV, x = idx % WV;
    int yf = y >> 2; if (yf > HF - 1) yf = HF - 1;
    int xf = x >> 2; if (xf > WF - 1) xf = WF - 1;
    int lin = yf * WF + xf;

    __shared__ float g[NC];
    g[tid] = features[((size_t)b * NC + tid) * (HF * WF) + lin];
    __syncthreads();

    float acc = 0.f;
    const float* wr = proj_w + (size_t)tid * NC;
    #pragma unroll 8
    for (int c = 0; c < NC; ++c) acc += g[c] * wr[c];

    out[((size_t)b * NSTORM + m) * NC + tid] = vld ? (acc + proj_b[tid]) : 0.f;

    if (tid == 0) {
        float* pos_out = out + (size_t)NB * NSTORM * NC;
        pos_out[(b * NSTORM + m) * 2 + 0] = (float)yf;
        pos_out[(b * NSTORM + m) * 2 + 1] = (float)xf;
        float* valid_out = pos_out + (size_t)NB * NSTORM * 2;
        valid_out[b * NSTORM + m] = vld ? 1.f : 0.f;
    }
}

extern "C" void kernel_launch(void* const* d_in, const int* in_sizes, int n_in,
                              void* d_out, int out_size, void* d_ws, size_t ws_size,
                              hipStream_t stream) {
    const float* features = (const float*)d_in[0];
    const float* vil      = (const float*)d_in[1];
    const float* proj_w   = (const float*)d_in[2];
    const float* proj_b   = (const float*)d_in[3];
    float* out = (float*)d_out;

    uint8_t* ws = (uint8_t*)d_ws;
    int* cnt       = (int*)ws;
    int* sel_idx   = (int*)(ws + 256);
    int* sel_valid = (int*)(ws + 256 + NB * NSTORM * sizeof(int));
    uint64_t* cand = (uint64_t*)(ws + 16384);

    size_t avail = (ws_size > 16384) ? (ws_size - 16384) : 0;
    int cap = (int)(avail / (NB * sizeof(uint64_t)));
    if (cap > 8192) cap = 8192;
    if (cap < 1)    cap = 1;

    hipMemsetAsync(cnt, 0, NB * sizeof(int), stream);

    dim3 gA(WV / TW, HV / TH, NB);        // 6 x 12 x 32
    peak_kernel<<<gA, 256, 0, stream>>>(vil, cand, cnt, cap);
    select_kernel<<<NB, 256, 0, stream>>>(cand, cnt, cap, vil, sel_idx, sel_valid);
    project_kernel<<<NB * NSTORM, 128, 0, stream>>>(features, proj_w, proj_b,
                                                    sel_idx, sel_valid, out);
}

// Round 3
// 98.439 us; speedup vs baseline: 6.6995x; 4.9690x over previous
//
#include <hip/hip_runtime.h>
#include <stdint.h>

#define HV 384
#define WV 384
#define HF 96
#define WF 96
#define NC 128
#define NB 32
#define NSTORM 50
#define TFRAMES 12
#define MIN_INT 0.3f

// peak tile geometry: each block produces a TH x TW block of the peak mask.
// Window is rows i-4..i+3, cols j-4..j+3 (lo=4, hi=3), symmetric reflect.
#define TW 64
#define TH 32
#define LCAP 256          // >= provable max peaks per tile (~153; spacing >= 4)
#define CNT_STRIDE 16     // one counter per 64B cacheline

__device__ __forceinline__ int reflect_idx(int g, int n) {
    if (g < 0) return -g - 1;
    if (g >= n) return 2 * n - 1 - g;
    return g;
}

// ---- slow scalar peak predicate, used only on the dead fallback path
__device__ __forceinline__ bool is_peak(const float* __restrict__ vb, int p) {
    int i = p / WV, j = p % WV;
    float v = vb[p];
    if (!(v > MIN_INT)) return false;
    for (int dr = -4; dr <= 3; ++dr) {
        const float* row = vb + reflect_idx(i + dr, HV) * WV;
        for (int dc = -4; dc <= 3; ++dc)
            if (row[reflect_idx(j + dc, WV)] > v) return false;
    }
    return true;
}

// ---- kernel 1: separable 8x8 max filter on LDS tiles; block-privatized
// compaction (LDS buffer + ONE global atomic per block — the per-peak global
// atomicAdd-with-return was the 415us stall in R2).
// key = (float_bits(v) << 32) | ~idx — strict total order, so selection is
// deterministic regardless of compaction order.
__global__ void peak_kernel(const float* __restrict__ vil,
                            uint64_t* __restrict__ cand,
                            int* __restrict__ cnt, int cap) {
    __shared__ float A[TH + 7][TW + 8];   // input tile + halo (cols padded)
    __shared__ float Bm[TH + 7][TW];      // horizontal max (rows keep halo)
    __shared__ uint64_t lkeys[LCAP];
    __shared__ int lcnt, base_s;

    int b = blockIdx.z;
    int tx0 = blockIdx.x * TW;
    int ty0 = blockIdx.y * TH;
    int tid = threadIdx.x;                // 256 threads
    const float* vb = vil + ((size_t)b * TFRAMES + (TFRAMES - 1)) * (HV * WV);

    if (tid == 0) lcnt = 0;

    for (int k = tid; k < (TH + 7) * (TW + 7); k += 256) {
        int r = k / (TW + 7), c = k % (TW + 7);
        int gr = reflect_idx(ty0 + r - 4, HV);
        int gc = reflect_idx(tx0 + c - 4, WV);
        A[r][c] = vb[gr * WV + gc];
    }
    __syncthreads();

    // horizontal: Bm[r][c] = max(A[r][c..c+7])
    for (int k = tid; k < (TH + 7) * TW; k += 256) {
        int r = k / TW, c = k % TW;
        float m = A[r][c];
        #pragma unroll
        for (int d = 1; d < 8; ++d) m = fmaxf(m, A[r][c + d]);
        Bm[r][c] = m;
    }
    __syncthreads();

    // vertical + predicate: out pixel (r,c) uses Bm rows r..r+7
    for (int k = tid; k < TH * TW; k += 256) {
        int r = k / TW, c = k % TW;
        float v = A[r + 4][c + 4];
        if (v > MIN_INT) {
            float m = Bm[r][c];
            #pragma unroll
            for (int d = 1; d < 8; ++d) m = fmaxf(m, Bm[r + d][c]);
            if (m <= v) {                  // window max == v -> peak
                int p = (ty0 + r) * WV + (tx0 + c);
                uint64_t key = ((uint64_t)__float_as_uint(v) << 32)
                             | (uint64_t)(0xFFFFFFFFu - (uint32_t)p);
                int pos = atomicAdd(&lcnt, 1);        // LDS atomic
                if (pos < LCAP) lkeys[pos] = key;
                else {                                 // unreachable safety path
                    int gp = atomicAdd(cnt + b * CNT_STRIDE, 1);
                    if (gp < cap) cand[(size_t)b * cap + gp] = key;
                }
            }
        }
    }
    __syncthreads();

    int take = lcnt < LCAP ? lcnt : LCAP;
    if (tid == 0) base_s = atomicAdd(cnt + b * CNT_STRIDE, take);
    __syncthreads();
    int base = base_s;
    for (int k = tid; k < take; k += 256) {
        int dst = base + k;
        if (dst < cap) cand[(size_t)b * cap + dst] = lkeys[k];
    }
}

// ---- kernel 2: per batch, top-50 keys (desc value, ties -> lower idx)
#define SEL_CAP 4096
__global__ void select_kernel(const uint64_t* __restrict__ cand,
                              const int* __restrict__ cnt, int cap,
                              const float* __restrict__ vil,
                              int* __restrict__ sel_idx,
                              int* __restrict__ sel_valid) {
    __shared__ uint64_t keys[SEL_CAP];    // 32 KB stage
    __shared__ uint64_t wred[4];
    __shared__ uint64_t bcast;

    int b = blockIdx.x;
    int tid = threadIdx.x;                // 256
    int n = cnt[b * CNT_STRIDE]; if (n > cap) n = cap;
    int K = n < NSTORM ? n : NSTORM;
    const uint64_t* ck = cand + (size_t)b * cap;

    bool lds = (n <= SEL_CAP);
    if (lds) for (int k = tid; k < n; k += 256) keys[k] = ck[k];
    __syncthreads();

    uint64_t prev = ~0ull;
    for (int t = 0; t < K; ++t) {
        uint64_t best = 0;
        if (lds) { for (int k = tid; k < n; k += 256) { uint64_t key = keys[k]; if (key < prev && key > best) best = key; } }
        else     { for (int k = tid; k < n; k += 256) { uint64_t key = ck[k];   if (key < prev && key > best) best = key; } }
        #pragma unroll
        for (int off = 32; off > 0; off >>= 1) {
            uint64_t o = __shfl_xor(best, off);
            if (o > best) best = o;
        }
        if ((tid & 63) == 0) wred[tid >> 6] = best;
        __syncthreads();
        if (tid == 0) {
            uint64_t w = wred[0];
            #pragma unroll
            for (int i = 1; i < 4; ++i) if (wred[i] > w) w = wred[i];
            bcast = w;
            sel_idx[b * NSTORM + t] = (int)(0xFFFFFFFFu - (uint32_t)(w & 0xFFFFFFFFu));
            sel_valid[b * NSTORM + t] = 1;
        }
        __syncthreads();
        prev = bcast;
    }

    // Fallback (dead with this data: ~1600 peaks/batch >> 50): top_k on -inf
    // rows yields ascending non-peak indices; zero peaks -> center, valid.
    if (tid == 0 && K < NSTORM) {
        const float* vb = vil + ((size_t)b * TFRAMES + (TFRAMES - 1)) * (HV * WV);
        int f = 0;
        for (int t = K; t < NSTORM; ++t) {
            while (f < HV * WV && is_peak(vb, f)) ++f;
            sel_idx[b * NSTORM + t] = f;
            sel_valid[b * NSTORM + t] = 0;
            ++f;
        }
        if (n == 0) {
            sel_idx[b * NSTORM + 0] = (HV / 2) * WV + (WV / 2);
            sel_valid[b * NSTORM + 0] = 1;
        }
    }
}

// ---- kernel 3: gather feature column + 128x128 matvec + bias
__global__ void project_kernel(const float* __restrict__ features,
                               const float* __restrict__ proj_w,
                               const float* __restrict__ proj_b,
                               const int* __restrict__ sel_idx,
                               const int* __restrict__ sel_valid,
                               float* __restrict__ out) {
    int blk = blockIdx.x;
    int b = blk / NSTORM;
    int m = blk % NSTORM;
    int tid = threadIdx.x;                // 0..127

    int idx = sel_idx[b * NSTORM + m];
    int vld = sel_valid[b * NSTORM + m];
    int y = idx / WV, x = idx % WV;
    int yf = y >> 2; if (yf > HF - 1) yf = HF - 1;
    int xf = x >> 2; if (xf > WF - 1) xf = WF - 1;
    int lin = yf * WF + xf;

    __shared__ float g[NC];
    g[tid] = features[((size_t)b * NC + tid) * (HF * WF) + lin];
    __syncthreads();

    float acc = 0.f;
    const float* wr = proj_w + (size_t)tid * NC;
    #pragma unroll 8
    for (int c = 0; c < NC; ++c) acc += g[c] * wr[c];

    out[((size_t)b * NSTORM + m) * NC + tid] = vld ? (acc + proj_b[tid]) : 0.f;

    if (tid == 0) {
        float* pos_out = out + (size_t)NB * NSTORM * NC;
        pos_out[(b * NSTORM + m) * 2 + 0] = (float)yf;
        pos_out[(b * NSTORM + m) * 2 + 1] = (float)xf;
        float* valid_out = pos_out + (size_t)NB * NSTORM * 2;
        valid_out[b * NSTORM + m] = vld ? 1.f : 0.f;
    }
}

extern "C" void kernel_launch(void* const* d_in, const int* in_sizes, int n_in,
                              void* d_out, int out_size, void* d_ws, size_t ws_size,
                              hipStream_t stream) {
    const float* features = (const float*)d_in[0];
    const float* vil      = (const float*)d_in[1];
    const float* proj_w   = (const float*)d_in[2];
    const float* proj_b   = (const float*)d_in[3];
    float* out = (float*)d_out;

    uint8_t* ws = (uint8_t*)d_ws;
    int* cnt       = (int*)ws;                        // 32 counters, 64B apart
    int* sel_idx   = (int*)(ws + 8192);               // 1600 ints
    int* sel_valid = (int*)(ws + 8192 + NB * NSTORM * sizeof(int));
    uint64_t* cand = (uint64_t*)(ws + 32768);

    size_t avail = (ws_size > 32768) ? (ws_size - 32768) : 0;
    int cap = (int)(avail / (NB * sizeof(uint64_t)));
    if (cap > 8192) cap = 8192;
    if (cap < 1)    cap = 1;

    hipMemsetAsync(cnt, 0, NB * CNT_STRIDE * sizeof(int), stream);

    dim3 gA(WV / TW, HV / TH, NB);        // 6 x 12 x 32
    peak_kernel<<<gA, 256, 0, stream>>>(vil, cand, cnt, cap);
    select_kernel<<<NB, 256, 0, stream>>>(cand, cnt, cap, vil, sel_idx, sel_valid);
    project_kernel<<<NB * NSTORM, 128, 0, stream>>>(features, proj_w, proj_b,
                                                    sel_idx, sel_valid, out);
}

// Round 4
// 77.804 us; speedup vs baseline: 8.4764x; 1.2652x over previous
//
#include <hip/hip_runtime.h>
#include <stdint.h>

#define HV 384
#define WV 384
#define HF 96
#define WF 96
#define NC 128
#define NB 32
#define NSTORM 50
#define TFRAMES 12
#define MIN_INT 0.3f

// peak tile geometry: each block produces a TH x TW block of the peak mask.
// Window is rows i-4..i+3, cols j-4..j+3 (lo=4, hi=3), symmetric reflect.
#define TW 64
#define TH 32
#define GX (WV / TW)      // 6 blocks across
#define LCAP 256          // >= provable max peaks per tile (~153; spacing >= 4)
#define CNT_STRIDE 16     // one counter per 64B cacheline

__device__ __forceinline__ int reflect_idx(int g, int n) {
    if (g < 0) return -g - 1;
    if (g >= n) return 2 * n - 1 - g;
    return g;
}

// ---- slow scalar peak predicate, used only on the dead fallback path
__device__ __forceinline__ bool is_peak(const float* __restrict__ vb, int p) {
    int i = p / WV, j = p % WV;
    float v = vb[p];
    if (!(v > MIN_INT)) return false;
    for (int dr = -4; dr <= 3; ++dr) {
        const float* row = vb + reflect_idx(i + dr, HV) * WV;
        for (int dc = -4; dc <= 3; ++dc)
            if (row[reflect_idx(j + dc, WV)] > v) return false;
    }
    return true;
}

// ---- kernel 1: separable 8x8 max filter on LDS tiles; float4 staging;
// block-privatized compaction (one global atomic per block).
// key = (float_bits(v) << 32) | ~idx — strict total order, so selection is
// deterministic regardless of compaction order.
__global__ void peak_kernel(const float* __restrict__ vil,
                            uint64_t* __restrict__ cand,
                            int* __restrict__ cnt, int cap) {
    __shared__ __align__(16) float A[TH + 7][TW + 8];  // tile + halo
    __shared__ float Bm[TH + 7][TW];                   // horizontal max
    __shared__ uint64_t lkeys[LCAP];
    __shared__ int lcnt, base_s;

    int b = blockIdx.z, bx = blockIdx.x;
    int tx0 = bx * TW, ty0 = blockIdx.y * TH;
    int tid = threadIdx.x;                 // 256 threads
    const float* vb = vil + ((size_t)b * TFRAMES + (TFRAMES - 1)) * (HV * WV);

    if (tid == 0) lcnt = 0;

    // float4 staging: columns [c0, c0+4*nf4) of the halo'd tile; row reflect
    // is pointer-only so it keeps 16B alignment. Only x-edge blocks have a
    // small scalar column remainder (<=4 cols).
    int c0   = (bx == 0) ? 0 : tx0 - 4;              // multiple of 4
    int nf4  = (bx == 0 || bx == GX - 1) ? 17 : 18;
    int aoff = c0 - (tx0 - 4);                        // 0 or 4
    for (int k = tid; k < (TH + 7) * nf4; k += 256) {
        int r = k / nf4, q = k - r * nf4;
        int gr = reflect_idx(ty0 + r - 4, HV);
        float4 vv = *(const float4*)(vb + (size_t)gr * WV + c0 + 4 * q);
        *(float4*)&A[r][aoff + 4 * q] = vv;
    }
    int nl = aoff;                          // left scalar cols [0, nl)
    int rstart = aoff + 4 * nf4;            // right scalar cols [rstart, 71)
    int nr = 71 - rstart; if (nr < 0) nr = 0;
    int ns = nl + nr;
    if (ns) for (int k = tid; k < (TH + 7) * ns; k += 256) {
        int r = k / ns, s = k - r * ns;
        int c = (s < nl) ? s : rstart + (s - nl);
        int gr = reflect_idx(ty0 + r - 4, HV);
        int gc = reflect_idx(tx0 + c - 4, WV);
        A[r][c] = vb[(size_t)gr * WV + gc];
    }
    __syncthreads();

    // horizontal: Bm[r][c] = max(A[r][c..c+7])
    for (int k = tid; k < (TH + 7) * TW; k += 256) {
        int r = k / TW, c = k % TW;
        float m = A[r][c];
        #pragma unroll
        for (int d = 1; d < 8; ++d) m = fmaxf(m, A[r][c + d]);
        Bm[r][c] = m;
    }
    __syncthreads();

    // vertical + predicate: out pixel (r,c) uses Bm rows r..r+7
    for (int k = tid; k < TH * TW; k += 256) {
        int r = k / TW, c = k % TW;
        float v = A[r + 4][c + 4];
        if (v > MIN_INT) {
            float m = Bm[r][c];
            #pragma unroll
            for (int d = 1; d < 8; ++d) m = fmaxf(m, Bm[r + d][c]);
            if (m <= v) {                  // window max == v -> peak
                int p = (ty0 + r) * WV + (tx0 + c);
                uint64_t key = ((uint64_t)__float_as_uint(v) << 32)
                             | (uint64_t)(0xFFFFFFFFu - (uint32_t)p);
                int pos = atomicAdd(&lcnt, 1);        // LDS atomic
                if (pos < LCAP) lkeys[pos] = key;
                else {                                 // unreachable safety path
                    int gp = atomicAdd(cnt + b * CNT_STRIDE, 1);
                    if (gp < cap) cand[(size_t)b * cap + gp] = key;
                }
            }
        }
    }
    __syncthreads();

    int take = lcnt < LCAP ? lcnt : LCAP;
    if (tid == 0) base_s = atomicAdd(cnt + b * CNT_STRIDE, take);
    __syncthreads();
    int base = base_s;
    for (int k = tid; k < take; k += 256) {
        int dst = base + k;
        if (dst < cap) cand[(size_t)b * cap + dst] = lkeys[k];
    }
}

// ---- kernel 2: per batch, top-50 keys (desc value, ties -> lower idx).
// 256-way merge: each thread insertion-sorts its <=16-key chunk into an LDS
// list ONCE; a single wave then pops 50 winners from the 256 list heads
// (no barriers, no rescans). Keys unique (idx in low bits), 0 = sentinel.
#define SEL_CAP 4096
#define LSTR 17            // list stride in u64 (max 16 entries + pad)
__global__ void select_kernel(const uint64_t* __restrict__ cand,
                              const int* __restrict__ cnt, int cap,
                              const float* __restrict__ vil,
                              int* __restrict__ sel_idx,
                              int* __restrict__ sel_valid) {
    __shared__ uint64_t lists[256 * LSTR];
    __shared__ uint64_t wred[4];
    __shared__ uint64_t bcast;

    int b = blockIdx.x;
    int tid = threadIdx.x;                 // 256
    int n = cnt[b * CNT_STRIDE]; if (n > cap) n = cap;
    int K = n < NSTORM ? n : NSTORM;
    const uint64_t* ck = cand + (size_t)b * cap;

    if (n <= SEL_CAP) {
        int S = (n <= 2048) ? 8 : 16;
        // per-thread insertion sort (descending) straight from global
        {
            int base = tid * LSTR, len = 0;
            for (int a = 0; a < S; ++a) {
                int g = tid * S + a;
                uint64_t key = (g < n) ? ck[g] : 0;
                int j = len - 1;
                while (j >= 0 && lists[base + j] < key) {
                    lists[base + j + 1] = lists[base + j]; --j;
                }
                lists[base + j + 1] = key; ++len;
            }
        }
        __syncthreads();
        // single-wave 256-way merge: lane owns 4 lists
        if (tid < 64) {
            uint64_t v[4]; int h[4];
            #pragma unroll
            for (int i = 0; i < 4; ++i) { h[i] = 0; v[i] = lists[(tid * 4 + i) * LSTR]; }
            for (int t = 0; t < K; ++t) {
                uint64_t best = v[0];
                #pragma unroll
                for (int i = 1; i < 4; ++i) if (v[i] > best) best = v[i];
                #pragma unroll
                for (int off = 32; off > 0; off >>= 1) {
                    uint64_t o = __shfl_xor(best, off);
                    if (o > best) best = o;
                }
                #pragma unroll
                for (int i = 0; i < 4; ++i) {
                    if (v[i] == best) {
                        ++h[i];
                        v[i] = (h[i] < S) ? lists[(tid * 4 + i) * LSTR + h[i]] : 0;
                    }
                }
                if (tid == 0) {
                    sel_idx[b * NSTORM + t] = (int)(~(uint32_t)(best & 0xFFFFFFFFu));
                    sel_valid[b * NSTORM + t] = 1;
                }
            }
        }
    } else {
        // dead safety path for n > SEL_CAP: iterative global rescan
        uint64_t prev = ~0ull;
        for (int t = 0; t < K; ++t) {
            uint64_t best = 0;
            for (int k = tid; k < n; k += 256) {
                uint64_t key = ck[k];
                if (key < prev && key > best) best = key;
            }
            #pragma unroll
            for (int off = 32; off > 0; off >>= 1) {
                uint64_t o = __shfl_xor(best, off);
                if (o > best) best = o;
            }
            if ((tid & 63) == 0) wred[tid >> 6] = best;
            __syncthreads();
            if (tid == 0) {
                uint64_t w = wred[0];
                #pragma unroll
                for (int i = 1; i < 4; ++i) if (wred[i] > w) w = wred[i];
                bcast = w;
                sel_idx[b * NSTORM + t] = (int)(~(uint32_t)(w & 0xFFFFFFFFu));
                sel_valid[b * NSTORM + t] = 1;
            }
            __syncthreads();
            prev = bcast;
        }
    }

    // Fallback (dead with this data: ~1600 peaks/batch >> 50): top_k on -inf
    // rows yields ascending non-peak indices; zero peaks -> center, valid.
    if (tid == 0 && K < NSTORM) {
        const float* vb = vil + ((size_t)b * TFRAMES + (TFRAMES - 1)) * (HV * WV);
        int f = 0;
        for (int t = K; t < NSTORM; ++t) {
            while (f < HV * WV && is_peak(vb, f)) ++f;
            sel_idx[b * NSTORM + t] = f;
            sel_valid[b * NSTORM + t] = 0;
            ++f;
        }
        if (n == 0) {
            sel_idx[b * NSTORM + 0] = (HV / 2) * WV + (WV / 2);
            sel_valid[b * NSTORM + 0] = 1;
        }
    }
}

// ---- kernel 3: gather feature column + 128x128 matvec + bias
__global__ void project_kernel(const float* __restrict__ features,
                               const float* __restrict__ proj_w,
                               const float* __restrict__ proj_b,
                               const int* __restrict__ sel_idx,
                               const int* __restrict__ sel_valid,
                               float* __restrict__ out) {
    int blk = blockIdx.x;
    int b = blk / NSTORM;
    int m = blk % NSTORM;
    int tid = threadIdx.x;                 // 0..127

    int idx = sel_idx[b * NSTORM + m];
    int vld = sel_valid[b * NSTORM + m];
    int y = idx / WV, x = idx % WV;
    int yf = y >> 2; if (yf > HF - 1) yf = HF - 1;
    int xf = x >> 2; if (xf > WF - 1) xf = WF - 1;
    int lin = yf * WF + xf;

    __shared__ float g[NC];
    g[tid] = features[((size_t)b * NC + tid) * (HF * WF) + lin];
    __syncthreads();

    float acc = 0.f;
    const float* wr = proj_w + (size_t)tid * NC;
    #pragma unroll 8
    for (int c = 0; c < NC; ++c) acc += g[c] * wr[c];

    out[((size_t)b * NSTORM + m) * NC + tid] = vld ? (acc + proj_b[tid]) : 0.f;

    if (tid == 0) {
        float* pos_out = out + (size_t)NB * NSTORM * NC;
        pos_out[(b * NSTORM + m) * 2 + 0] = (float)yf;
        pos_out[(b * NSTORM + m) * 2 + 1] = (float)xf;
        float* valid_out = pos_out + (size_t)NB * NSTORM * 2;
        valid_out[b * NSTORM + m] = vld ? 1.f : 0.f;
    }
}

extern "C" void kernel_launch(void* const* d_in, const int* in_sizes, int n_in,
                              void* d_out, int out_size, void* d_ws, size_t ws_size,
                              hipStream_t stream) {
    const float* features = (const float*)d_in[0];
    const float* vil      = (const float*)d_in[1];
    const float* proj_w   = (const float*)d_in[2];
    const float* proj_b   = (const float*)d_in[3];
    float* out = (float*)d_out;

    uint8_t* ws = (uint8_t*)d_ws;
    int* cnt       = (int*)ws;                        // 32 counters, 64B apart
    int* sel_idx   = (int*)(ws + 8192);               // 1600 ints
    int* sel_valid = (int*)(ws + 8192 + NB * NSTORM * sizeof(int));
    uint64_t* cand = (uint64_t*)(ws + 32768);

    size_t avail = (ws_size > 32768) ? (ws_size - 32768) : 0;
    int cap = (int)(avail / (NB * sizeof(uint64_t)));
    if (cap > 8192) cap = 8192;
    if (cap < 1)    cap = 1;

    hipMemsetAsync(cnt, 0, NB * CNT_STRIDE * sizeof(int), stream);

    dim3 gA(GX, HV / TH, NB);              // 6 x 12 x 32
    peak_kernel<<<gA, 256, 0, stream>>>(vil, cand, cnt, cap);
    select_kernel<<<NB, 256, 0, stream>>>(cand, cnt, cap, vil, sel_idx, sel_valid);
    project_kernel<<<NB * NSTORM, 128, 0, stream>>>(features, proj_w, proj_b,
                                                    sel_idx, sel_valid, out);
}